// Round 3
// baseline (357.645 us; speedup 1.0000x reference)
//
#include <hip/hip_runtime.h>
#include <hip/hip_bf16.h>
#include <stdint.h>

typedef unsigned short u16;
typedef short short8 __attribute__((ext_vector_type(8)));
typedef float floatx4 __attribute__((ext_vector_type(4)));

#define NPERB   40000
#define NPTS    80000
#define KNBR    16
#define CIN     64
#define MDIM    16
#define CADD    3
#define CF      (CIN + CADD)     // 67
#define COUT    128
#define KF      1072
#define KP      1088

__device__ __forceinline__ u16 f2bf(float f) {
    union { float f; unsigned int u; } v; v.f = f;
    unsigned int u = v.u;
    return (u16)((u + 0x7FFFu + ((u >> 16) & 1u)) >> 16);
}
__device__ __forceinline__ short8 pack8(floatx4 x, floatx4 y) {
    union { short8 v; u16 a[8]; } u;
    u.a[0] = f2bf(x[0]); u.a[1] = f2bf(x[1]); u.a[2] = f2bf(x[2]); u.a[3] = f2bf(x[3]);
    u.a[4] = f2bf(y[0]); u.a[5] = f2bf(y[1]); u.a[6] = f2bf(y[2]); u.a[7] = f2bf(y[3]);
    return u.v;
}

// Convert+pad linear_weight fp32 [128,1072] -> bf16 ws [128,1088] (zero pad).
__global__ void prep_lw_kernel(const float* __restrict__ lw, u16* __restrict__ lwp) {
    int i = blockIdx.x * 256 + threadIdx.x;
    if (i >= COUT * KP) return;
    int o = i / KP, f = i - o * KP;
    lwp[i] = (f < KF) ? f2bf(lw[(size_t)o * KF + f]) : (u16)0;
}

// Stage 1: one wave per point. lane = channel (0..63 gathered; lanes 0..2 also
// do the 3 additional channels). Writes pconv row [KP] bf16, zero-padded.
__global__ __launch_bounds__(256) void stage1_kernel(
    const float* __restrict__ inp,   // [2,40000,64] fp32
    const int*   __restrict__ nbr,   // [2,40000,16] int32
    const float* __restrict__ wn,    // [2,40000,16,16] fp32
    const float* __restrict__ addl,  // [2,40000,16,3] fp32
    u16* __restrict__ pc,            // [count, KP] bf16 (chunk-local)
    int chunk_start, int count)
{
    __shared__ __align__(16) float wsm[4][KNBR * MDIM];
    const int wave = threadIdx.x >> 6;
    const int lane = threadIdx.x & 63;
    const int lp = blockIdx.x * 4 + wave;   // local point in chunk
    const int p = chunk_start + lp;         // global point
    const int b = p / NPERB;

    // stage this point's weightnet (16x16 fp32) into LDS
    {
        const floatx4* wn4 = (const floatx4*)(wn + (size_t)p * (KNBR * MDIM));
        ((floatx4*)&wsm[wave][0])[lane] = wn4[lane];
    }
    __syncthreads();

    const floatx4* wrow = (const floatx4*)&wsm[wave][0];
    const float* inpb = inp + (size_t)b * NPERB * CIN;
    const int* nbrp = nbr + (size_t)p * KNBR;

    floatx4 a0 = 0, a1 = 0, a2 = 0, a3 = 0;   // pconv[c=lane][m=0..15]
#pragma unroll
    for (int k = 0; k < KNBR; k++) {
        int idx = nbrp[k];
        float fv = inpb[(size_t)idx * CIN + lane];   // coalesced 256B/wave
        a0 += fv * wrow[k * 4 + 0];
        a1 += fv * wrow[k * 4 + 1];
        a2 += fv * wrow[k * 4 + 2];
        a3 += fv * wrow[k * 4 + 3];
    }

    u16* row = pc + (size_t)lp * KP;
    *(short8*)(row + lane * 16)     = pack8(a0, a1);
    *(short8*)(row + lane * 16 + 8) = pack8(a2, a3);

    if (lane < CADD) {
        // channels 64..66 from additional_features
        const float* ap = addl + (size_t)p * (KNBR * CADD) + lane;
        floatx4 c0 = 0, c1 = 0, c2 = 0, c3 = 0;
#pragma unroll
        for (int k = 0; k < KNBR; k++) {
            float av = ap[(size_t)k * CADD];
            c0 += av * wrow[k * 4 + 0];
            c1 += av * wrow[k * 4 + 1];
            c2 += av * wrow[k * 4 + 2];
            c3 += av * wrow[k * 4 + 3];
        }
        u16* r2 = row + CIN * MDIM + lane * 16;   // f = 1024 + lane*16
        *(short8*)(r2)     = pack8(c0, c1);
        *(short8*)(r2 + 8) = pack8(c2, c3);
    } else if (lane == CADD) {
        // zero the pad f = 1072..1087
        short8 z = {0,0,0,0,0,0,0,0};
        *(short8*)(row + KF)     = z;
        *(short8*)(row + KF + 8) = z;
    }
}

// Stage 2: out[p,o] = sum_f pconv[p,f]*LW[o,f] + bias[o].  fp32 out.
// Block = 4 waves; block tile 128 points x 128 cols; wave tile 64x64.
// mfma_f32_16x16x32_bf16: A[i=lane&15][k=quad*8+j], B[k=quad*8+j][n=lane&15],
// D[row=quad*4+r][col=lane&15]  (m89/m91-verified layouts).
__global__ __launch_bounds__(256) void stage2_kernel(
    const u16*   __restrict__ pc,    // [count, KP] bf16
    const u16*   __restrict__ lwp,   // [128, KP] bf16
    const float* __restrict__ bias,  // [128] fp32
    float* __restrict__ out,         // [80000, 128] fp32
    int chunk_start, int count)
{
    const int wave = threadIdx.x >> 6;
    const int lane = threadIdx.x & 63;
    const int r16  = lane & 15;
    const int quad = lane >> 4;
    const int r0 = blockIdx.x * 128 + (wave >> 1) * 64;  // local row base
    const int c0 = (wave & 1) * 64;                      // col base

    const u16* Abase = pc  + (size_t)(r0 + r16) * KP + quad * 8;
    const u16* Bbase = lwp + (size_t)(c0 + r16) * KP + quad * 8;

    floatx4 acc[4][4];
#pragma unroll
    for (int i = 0; i < 4; i++)
#pragma unroll
        for (int j = 0; j < 4; j++) acc[i][j] = 0;

#pragma unroll 2
    for (int kt = 0; kt < KP / 32; kt++) {
        short8 a[4], b[4];
#pragma unroll
        for (int i = 0; i < 4; i++)
            a[i] = *(const short8*)(Abase + (size_t)i * 16 * KP + kt * 32);
#pragma unroll
        for (int j = 0; j < 4; j++)
            b[j] = *(const short8*)(Bbase + (size_t)j * 16 * KP + kt * 32);
#pragma unroll
        for (int i = 0; i < 4; i++)
#pragma unroll
            for (int j = 0; j < 4; j++)
                acc[i][j] = __builtin_amdgcn_mfma_f32_16x16x32_bf16(
                    a[i], b[j], acc[i][j], 0, 0, 0);
    }

    const int p0 = chunk_start + r0;
#pragma unroll
    for (int j = 0; j < 4; j++) {
        int col = c0 + j * 16 + r16;
        float bv = bias[col];
#pragma unroll
        for (int i = 0; i < 4; i++) {
#pragma unroll
            for (int r = 0; r < 4; r++) {
                int prow = p0 + i * 16 + quad * 4 + r;
                out[(size_t)prow * COUT + col] = acc[i][j][r] + bv;
            }
        }
    }
}

// No-workspace fallback (only if ws_size is too small): one block per point,
// all-fp32 via LDS. Slow but correct.
__global__ __launch_bounds__(256) void fused_fallback_kernel(
    const float* __restrict__ inp, const int* __restrict__ nbr,
    const float* __restrict__ wn, const float* __restrict__ addl,
    const float* __restrict__ lw, const float* __restrict__ bias,
    float* __restrict__ out)
{
    const int p = blockIdx.x;
    const int b = p / NPERB;
    const int tid = threadIdx.x;
    __shared__ float sf[KNBR * CF];     // feats, k-major
    __shared__ float sw[KNBR * MDIM];   // weightnet
    __shared__ float sp[KF];            // pconv, f = c*16+m

    sw[tid] = wn[(size_t)p * (KNBR * MDIM) + tid];
    for (int i = tid; i < KNBR * CIN; i += 256) {
        int k = i >> 6, c = i & 63;
        int idx = nbr[(size_t)p * KNBR + k];
        sf[k * CF + c] = inp[((size_t)b * NPERB + idx) * CIN + c];
    }
    if (tid < KNBR * CADD) {
        int k = tid / CADD, c = tid - k * CADD;
        sf[k * CF + CIN + c] = addl[(size_t)p * (KNBR * CADD) + tid];
    }
    __syncthreads();
    for (int f = tid; f < KF; f += 256) {
        int c = f >> 4, m = f & 15;
        float s = 0;
#pragma unroll
        for (int k = 0; k < KNBR; k++) s += sf[k * CF + c] * sw[k * MDIM + m];
        sp[f] = s;
    }
    __syncthreads();
    const int o = tid >> 1, h = tid & 1;
    float s = 0;
    for (int f = h * (KF / 2); f < (h + 1) * (KF / 2); f++)
        s += sp[f] * lw[(size_t)o * KF + f];
    s += __shfl_xor(s, 1);
    if (h == 0) out[(size_t)p * COUT + o] = s + bias[o];
}

extern "C" void kernel_launch(void* const* d_in, const int* in_sizes, int n_in,
                              void* d_out, int out_size, void* d_ws, size_t ws_size,
                              hipStream_t stream) {
    const float* inp  = (const float*)d_in[0];
    const int*   nbr  = (const int*)d_in[1];
    // d_in[2..4] = inverse_* (backward-only, unused)
    const float* wn   = (const float*)d_in[5];
    const float* addl = (const float*)d_in[6];
    const float* lw   = (const float*)d_in[7];
    const float* bias = (const float*)d_in[8];
    float* out = (float*)d_out;

    const size_t lw_bytes = (size_t)COUT * KP * sizeof(u16);  // 278528
    const size_t row_bytes = (size_t)KP * sizeof(u16);        // 2176

    size_t need_min = lw_bytes + 128 * row_bytes;
    if (ws_size < need_min) {
        // workspace too small for the staged pipeline — correct fallback
        fused_fallback_kernel<<<NPTS, 256, 0, stream>>>(inp, nbr, wn, addl, lw, bias, out);
        return;
    }

    u16* lwp = (u16*)d_ws;
    u16* pc  = (u16*)((char*)d_ws + lw_bytes);

    size_t avail = ws_size - lw_bytes;
    long long maxc = (long long)(avail / row_bytes);
    maxc = (maxc / 128) * 128;
    int chunk = (maxc >= NPTS) ? NPTS : (int)maxc;

    prep_lw_kernel<<<(COUT * KP + 255) / 256, 256, 0, stream>>>(lw, lwp);
    for (int start = 0; start < NPTS; start += chunk) {
        int count = NPTS - start;
        if (count > chunk) count = chunk;
        stage1_kernel<<<count / 4, 256, 0, stream>>>(inp, nbr, wn, addl, pc, start, count);
        stage2_kernel<<<count / 128, 256, 0, stream>>>(pc, lwp, bias, out, start, count);
    }
}